// Round 1
// baseline (1194.347 us; speedup 1.0000x reference)
//
#include <hip/hip_runtime.h>
#include <math.h>

#define DIM 2048
#define NC  1024
#define NP  64
#define MAPLEN 256
#define KTOT (NP * MAPLEN)   // 16384

// ---------------------------------------------------------------------------
// Stage 1: sims[c] = dot(h, centroids[:,c]) / ||centroids[:,c]||
// centroids layout: [D, C] row-major -> element (d,c) at d*NC + c
// one block per cluster, 256 threads
// ---------------------------------------------------------------------------
__global__ __launch_bounds__(256) void sims_kernel(const float* __restrict__ h,
                                                   const float* __restrict__ cent,
                                                   float* __restrict__ sims) {
    int c = blockIdx.x;
    int tid = threadIdx.x;
    float dot = 0.f, nrm = 0.f;
    for (int d = tid; d < DIM; d += 256) {
        float v = cent[(size_t)d * NC + c];
        dot += v * h[d];
        nrm += v * v;
    }
    // wave (64-lane) reduce
    for (int off = 32; off > 0; off >>= 1) {
        dot += __shfl_down(dot, off);
        nrm += __shfl_down(nrm, off);
    }
    __shared__ float sd[4], sn[4];
    int wave = tid >> 6, lane = tid & 63;
    if (lane == 0) { sd[wave] = dot; sn[wave] = nrm; }
    __syncthreads();
    if (tid == 0) {
        float td = sd[0] + sd[1] + sd[2] + sd[3];
        float tn = sn[0] + sn[1] + sn[2] + sn[3];
        sims[c] = td / sqrtf(tn);
    }
}

// ---------------------------------------------------------------------------
// Stage 2: top-64 by rank-selection (matches jax.lax.top_k ordering:
// descending value, ties -> lower index first), then gather vocab_maps rows.
// single block, 1024 threads.
// ---------------------------------------------------------------------------
__global__ __launch_bounds__(1024) void topk_gather_kernel(const float* __restrict__ sims,
                                                           const int* __restrict__ vmaps,
                                                           int* __restrict__ indices) {
    __shared__ float s_sims[NC];
    __shared__ int s_top[NP];
    int tid = threadIdx.x;
    s_sims[tid] = sims[tid];
    __syncthreads();
    float my = s_sims[tid];
    int rank = 0;
    for (int j = 0; j < NC; ++j) {
        float v = s_sims[j];  // same address across all lanes -> LDS broadcast
        rank += (v > my) || (v == my && j < tid);
    }
    if (rank < NP) s_top[rank] = tid;
    __syncthreads();
    for (int k = tid; k < KTOT; k += 1024) {
        int p = k >> 8, j = k & 255;
        indices[k] = vmaps[s_top[p] * MAPLEN + j];
    }
}

// ---------------------------------------------------------------------------
// Stage 3: logits[k] = dot(h, lm_head[indices[k]]) -> d_out[1+k]
// 1 row per wave, 4 waves per block, float4 coalesced row reads. HBM-bound.
// ---------------------------------------------------------------------------
__global__ __launch_bounds__(256) void logits_kernel(const float* __restrict__ h,
                                                     const float* __restrict__ lm,
                                                     const int* __restrict__ indices,
                                                     float* __restrict__ out) {
    __shared__ float4 s_h[DIM / 4];   // 8 KB
    int tid = threadIdx.x;
    const float4* h4 = (const float4*)h;
    for (int i = tid; i < DIM / 4; i += 256) s_h[i] = h4[i];
    __syncthreads();
    int wave = tid >> 6, lane = tid & 63;
    int row = blockIdx.x * 4 + wave;
    int tok = indices[row];
    const float4* w4 = (const float4*)(lm + (size_t)tok * DIM);
    float acc = 0.f;
    #pragma unroll
    for (int i = lane; i < DIM / 4; i += 64) {   // 8 iterations
        float4 a = w4[i];
        float4 b = s_h[i];
        acc += a.x * b.x + a.y * b.y + a.z * b.z + a.w * b.w;
    }
    for (int off = 32; off > 0; off >>= 1) acc += __shfl_down(acc, off);
    if (lane == 0) out[1 + row] = acc;
}

// ---------------------------------------------------------------------------
// Stage 4: argmax over 16384 logits (first occurrence on ties), write token.
// single block, 1024 threads.
// ---------------------------------------------------------------------------
__global__ __launch_bounds__(1024) void argmax_kernel(const int* __restrict__ indices,
                                                      float* __restrict__ out) {
    __shared__ float s_v[1024];
    __shared__ int s_i[1024];
    int tid = threadIdx.x;
    float best = -INFINITY;
    int bi = KTOT;
    for (int k = tid; k < KTOT; k += 1024) {
        float v = out[1 + k];
        if (v > best) { best = v; bi = k; }   // strictly greater keeps earliest k
    }
    s_v[tid] = best; s_i[tid] = bi;
    __syncthreads();
    for (int s = 512; s > 0; s >>= 1) {
        if (tid < s) {
            float v2 = s_v[tid + s]; int i2 = s_i[tid + s];
            if (v2 > s_v[tid] || (v2 == s_v[tid] && i2 < s_i[tid])) {
                s_v[tid] = v2; s_i[tid] = i2;
            }
        }
        __syncthreads();
    }
    if (tid == 0) out[0] = (float)indices[s_i[0]];
}

extern "C" void kernel_launch(void* const* d_in, const int* in_sizes, int n_in,
                              void* d_out, int out_size, void* d_ws, size_t ws_size,
                              hipStream_t stream) {
    const float* h     = (const float*)d_in[0];   // [1,1,2048] f32
    const float* lm    = (const float*)d_in[1];   // [128000,2048] f32
    const float* cent  = (const float*)d_in[2];   // [2048,1024] f32
    const int*   vmaps = (const int*)d_in[3];     // [1024,256] i32

    float* out = (float*)d_out;                   // [0]=token, [1..16384]=logits
    float* sims    = (float*)d_ws;                           // 4 KB
    int*   indices = (int*)((char*)d_ws + 4096);             // 64 KB

    sims_kernel<<<NC, 256, 0, stream>>>(h, cent, sims);
    topk_gather_kernel<<<1, 1024, 0, stream>>>(sims, vmaps, indices);
    logits_kernel<<<KTOT / 4, 256, 0, stream>>>(h, lm, indices, out);
    argmax_kernel<<<1, 1024, 0, stream>>>(indices, out);
}